// Round 3
// baseline (918.410 us; speedup 1.0000x reference)
//
#include <hip/hip_runtime.h>
#include <cstdint>

// LNGRU2dCell: B=16384, D=1024, S=1024
//   M1 = x @ Wi^T          (16384x4096, K=1024)
//   M2 = [s0|s1] @ Ws^T    (16384x4096, K=2048)
//   gates = LN(M1)*g1+b1 + LN(M2)*g2+b2 ; gate math ; out = LN(h)*gh+bh
//
// ws usage: EXACTLY 256 MB: M1 region [0,128MB) + M2 region [128,256MB).
//   phase 1: cast s-concat + Ws to bf16 INTO the M1 region (dead until GEMM1)
//   phase 2: GEMM2 bf16 fast path (global_load_lds w=16) -> M2
//   phase 3: GEMM1 stages raw fp32 x/Wi, packs bf16 frags in-register -> M1
//            (clobbers sb/Wsb, which are dead after phase 2)
//   phase 4: fused LN+gates+LN epilogue

typedef unsigned short ushort_t;
typedef __attribute__((ext_vector_type(8))) __bf16 bf16x8;
typedef __attribute__((ext_vector_type(4))) float f32x4;

__device__ __forceinline__ ushort_t f2b(float f) {  // RNE
    unsigned u = __float_as_uint(f);
    unsigned r = (u + 0x7fffu + ((u >> 16) & 1u)) >> 16;
    return (ushort_t)r;
}
__device__ __forceinline__ float b2f(ushort_t u) {
    return __uint_as_float(((unsigned)u) << 16);
}

__device__ __forceinline__ void gl_lds16(const void* g, void* l) {
    __builtin_amdgcn_global_load_lds(
        (const __attribute__((address_space(1))) unsigned int*)(uintptr_t)g,
        (__attribute__((address_space(3))) unsigned int*)(uintptr_t)l,
        16, 0, 0);
}

// pack 8 f32 -> 8 bf16 by truncation (v_perm): bias cancels under LayerNorm
__device__ __forceinline__ bf16x8 pack8(f32x4 lo, f32x4 hi) {
    union { unsigned u[4]; bf16x8 v; } r;
    r.u[0] = __builtin_amdgcn_perm(__float_as_uint(lo.y), __float_as_uint(lo.x), 0x07060302u);
    r.u[1] = __builtin_amdgcn_perm(__float_as_uint(lo.w), __float_as_uint(lo.z), 0x07060302u);
    r.u[2] = __builtin_amdgcn_perm(__float_as_uint(hi.y), __float_as_uint(hi.x), 0x07060302u);
    r.u[3] = __builtin_amdgcn_perm(__float_as_uint(hi.w), __float_as_uint(hi.z), 0x07060302u);
    return r.v;
}

// ---------------- casts ----------------
__global__ __launch_bounds__(256) void cast_bf16(const float* __restrict__ src,
                                                 ushort_t* __restrict__ dst, long n) {
    long i = ((long)blockIdx.x * 256 + threadIdx.x) * 4;
    if (i + 3 < n) {
        float4 v = *(const float4*)(src + i);
        ushort4 u;
        u.x = f2b(v.x); u.y = f2b(v.y); u.z = f2b(v.z); u.w = f2b(v.w);
        *(ushort4*)(dst + i) = u;
    }
}

// dst is B x 2048, src0/src1 are B x 1024 each
__global__ __launch_bounds__(256) void cast_concat(const float* __restrict__ s0,
                                                   const float* __restrict__ s1,
                                                   ushort_t* __restrict__ dst) {
    long i = ((long)blockIdx.x * 256 + threadIdx.x) * 4;  // index in dst
    long row = i >> 11;
    int  col = (int)(i & 2047);
    const float* src = (col < 1024) ? (s0 + row * 1024 + col)
                                    : (s1 + row * 1024 + (col - 1024));
    float4 v = *(const float4*)src;
    ushort4 u;
    u.x = f2b(v.x); u.y = f2b(v.y); u.z = f2b(v.z); u.w = f2b(v.w);
    *(ushort4*)(dst + i) = u;
}

// ------- GEMM (bf16 in): C[MxN] = A[MxK] @ W[NxK]^T, fp32 accum, bf16 out ---
__global__ __launch_bounds__(256, 2) void gemm_bt(const ushort_t* __restrict__ A,
                                                  const ushort_t* __restrict__ W,
                                                  ushort_t* __restrict__ C,
                                                  int M, int N, int K) {
    __shared__ __align__(16) ushort_t As[128 * 32];
    __shared__ __align__(16) ushort_t Bs[128 * 32];

    const int t    = threadIdx.x;
    const int lane = t & 63;
    const int wave = t >> 6;
    const int wm   = (wave >> 1) * 64;
    const int wn   = (wave & 1) * 64;

    const int bm0 = blockIdx.y * 128;
    const int bn0 = blockIdx.x * 128;

    // staging: thread t stages row t>>2, cols (t&3)*8 .. +7 (16 B)
    const int sr = t >> 2;
    const int sc = (t & 3) * 8;
    const ushort_t* Ag = A + (long)(bm0 + sr) * K + sc;
    const ushort_t* Wg = W + (long)(bn0 + sr) * K + sc;

    f32x4 acc[4][4];
#pragma unroll
    for (int i = 0; i < 4; i++)
#pragma unroll
        for (int j = 0; j < 4; j++) acc[i][j] = (f32x4){0.f, 0.f, 0.f, 0.f};

    const int mrow = lane & 15;
    const int kgrp = (lane >> 4) * 8;

    for (int k0 = 0; k0 < K; k0 += 32) {
        gl_lds16(Ag + k0,                As + t * 8);
        gl_lds16(Ag + (long)64 * K + k0, As + 2048 + t * 8);
        gl_lds16(Wg + k0,                Bs + t * 8);
        gl_lds16(Wg + (long)64 * K + k0, Bs + 2048 + t * 8);
        __syncthreads();

        bf16x8 af[4], bfr[4];
#pragma unroll
        for (int i = 0; i < 4; i++)
            af[i] = *(const bf16x8*)&As[(wm + i * 16 + mrow) * 32 + kgrp];
#pragma unroll
        for (int j = 0; j < 4; j++)
            bfr[j] = *(const bf16x8*)&Bs[(wn + j * 16 + mrow) * 32 + kgrp];
#pragma unroll
        for (int i = 0; i < 4; i++)
#pragma unroll
            for (int j = 0; j < 4; j++)
                acc[i][j] = __builtin_amdgcn_mfma_f32_16x16x32_bf16(af[i], bfr[j], acc[i][j], 0, 0, 0);
        __syncthreads();
    }

    // C/D layout: col=lane&15, row=(lane>>4)*4+r  [m89/m91 verified]
    const int quad = lane >> 4;
#pragma unroll
    for (int i = 0; i < 4; i++)
#pragma unroll
        for (int j = 0; j < 4; j++)
#pragma unroll
            for (int r = 0; r < 4; r++) {
                int cm = bm0 + wm + i * 16 + quad * 4 + r;
                int cn = bn0 + wn + j * 16 + (lane & 15);
                C[(long)cm * N + cn] = f2b(acc[i][j][r]);
            }
}

// ------- GEMM (fp32 in): stages fp32 tiles, packs bf16 frags in-register ----
__global__ __launch_bounds__(256, 2) void gemm_bt_f32(const float* __restrict__ A,
                                                      const float* __restrict__ W,
                                                      ushort_t* __restrict__ C,
                                                      int M, int N, int K) {
    __shared__ __align__(16) float As[128 * 32];
    __shared__ __align__(16) float Bs[128 * 32];

    const int t    = threadIdx.x;
    const int lane = t & 63;
    const int wave = t >> 6;
    const int wm   = (wave >> 1) * 64;
    const int wn   = (wave & 1) * 64;

    const int bm0 = blockIdx.y * 128;
    const int bn0 = blockIdx.x * 128;

    f32x4 acc[4][4];
#pragma unroll
    for (int i = 0; i < 4; i++)
#pragma unroll
        for (int j = 0; j < 4; j++) acc[i][j] = (f32x4){0.f, 0.f, 0.f, 0.f};

    const int mrow = lane & 15;
    const int kofs = (lane >> 4) * 8;  // float index within the 32-wide K tile

    for (int k0 = 0; k0 < K; k0 += 32) {
        // stage 128x32 fp32 per matrix: 1024 chunks of 16B, 4 chunks/thread
#pragma unroll
        for (int q = 0; q < 4; q++) {
            int id = q * 256 + t;          // chunk id: lane-contiguous per call
            int r  = id >> 3;              // row 0..127
            int c  = (id & 7) * 4;         // col 0,4,..,28
            gl_lds16(A + (long)(bm0 + r) * K + k0 + c, As + (size_t)id * 4);
            gl_lds16(W + (long)(bn0 + r) * K + k0 + c, Bs + (size_t)id * 4);
        }
        __syncthreads();

        bf16x8 af[4], bfr[4];
#pragma unroll
        for (int i = 0; i < 4; i++) {
            const float* p = &As[(wm + i * 16 + mrow) * 32 + kofs];
            af[i] = pack8(*(const f32x4*)p, *(const f32x4*)(p + 4));
        }
#pragma unroll
        for (int j = 0; j < 4; j++) {
            const float* p = &Bs[(wn + j * 16 + mrow) * 32 + kofs];
            bfr[j] = pack8(*(const f32x4*)p, *(const f32x4*)(p + 4));
        }
#pragma unroll
        for (int i = 0; i < 4; i++)
#pragma unroll
            for (int j = 0; j < 4; j++)
                acc[i][j] = __builtin_amdgcn_mfma_f32_16x16x32_bf16(af[i], bfr[j], acc[i][j], 0, 0, 0);
        __syncthreads();
    }

    const int quad = lane >> 4;
#pragma unroll
    for (int i = 0; i < 4; i++)
#pragma unroll
        for (int j = 0; j < 4; j++)
#pragma unroll
            for (int r = 0; r < 4; r++) {
                int cm = bm0 + wm + i * 16 + quad * 4 + r;
                int cn = bn0 + wn + j * 16 + (lane & 15);
                C[(long)cm * N + cn] = f2b(acc[i][j][r]);
            }
}

// ---------------- fused LN(M1)+LN(M2) -> gates -> h -> LN(h) ----------------
__global__ __launch_bounds__(256) void fuse_ln(const ushort_t* __restrict__ M1,
                                               const ushort_t* __restrict__ M2,
                                               const float* __restrict__ p0,
                                               const float* __restrict__ p1,
                                               const float* __restrict__ lni_g,
                                               const float* __restrict__ lni_b,
                                               const float* __restrict__ lns_g,
                                               const float* __restrict__ lns_b,
                                               const float* __restrict__ lnh_g,
                                               const float* __restrict__ lnh_b,
                                               float* __restrict__ out) {
    const int row = blockIdx.x;
    const int t   = threadIdx.x;
    const long base = (long)row * 4096;

    __shared__ float sred[16];
    __shared__ float stats[8];

    float v1[4][4], v2[4][4];
    float s1 = 0.f, q1 = 0.f, s2 = 0.f, q2 = 0.f;
#pragma unroll
    for (int q = 0; q < 4; q++) {
        ushort4 a = *(const ushort4*)(M1 + base + q * 1024 + t * 4);
        ushort4 b = *(const ushort4*)(M2 + base + q * 1024 + t * 4);
        const ushort_t* ap = (const ushort_t*)&a;
        const ushort_t* bp = (const ushort_t*)&b;
#pragma unroll
        for (int j = 0; j < 4; j++) {
            float f1 = b2f(ap[j]); v1[q][j] = f1; s1 += f1; q1 += f1 * f1;
            float f2 = b2f(bp[j]); v2[q][j] = f2; s2 += f2; q2 += f2 * f2;
        }
    }
    float r4[4] = {s1, q1, s2, q2};
#pragma unroll
    for (int off = 32; off > 0; off >>= 1) {
#pragma unroll
        for (int i = 0; i < 4; i++) r4[i] += __shfl_down(r4[i], off, 64);
    }
    if ((t & 63) == 0) {
        int w = t >> 6;
#pragma unroll
        for (int i = 0; i < 4; i++) sred[w * 4 + i] = r4[i];
    }
    __syncthreads();
    if (t == 0) {
        float S1 = 0, Q1 = 0, S2 = 0, Q2 = 0;
        for (int w = 0; w < 4; w++) {
            S1 += sred[w * 4]; Q1 += sred[w * 4 + 1];
            S2 += sred[w * 4 + 2]; Q2 += sred[w * 4 + 3];
        }
        float mu1 = S1 * (1.f / 4096.f), mu2 = S2 * (1.f / 4096.f);
        float var1 = Q1 * (1.f / 4096.f) - mu1 * mu1;
        float var2 = Q2 * (1.f / 4096.f) - mu2 * mu2;
        stats[0] = mu1; stats[1] = rsqrtf(var1 + 1e-5f);
        stats[2] = mu2; stats[3] = rsqrtf(var2 + 1e-5f);
    }
    __syncthreads();
    const float mu1 = stats[0], rs1 = stats[1], mu2 = stats[2], rs2 = stats[3];

    float4 Gi[4], Bi[4], Gs[4], Bs[4];
#pragma unroll
    for (int q = 0; q < 4; q++) {
        Gi[q] = *(const float4*)(lni_g + q * 1024 + t * 4);
        Bi[q] = *(const float4*)(lni_b + q * 1024 + t * 4);
        Gs[q] = *(const float4*)(lns_g + q * 1024 + t * 4);
        Bs[q] = *(const float4*)(lns_b + q * 1024 + t * 4);
    }
    float4 P0 = *(const float4*)(p0 + (long)row * 1024 + t * 4);
    float4 P1 = *(const float4*)(p1 + (long)row * 1024 + t * 4);

    float h[4];
    float sh = 0.f, qh = 0.f;
#pragma unroll
    for (int j = 0; j < 4; j++) {
        float gq[4], snv = 0.f;
#pragma unroll
        for (int q = 0; q < 4; q++) {
            float a = (v1[q][j] - mu1) * rs1 * ((const float*)&Gi[q])[j] + ((const float*)&Bi[q])[j];
            float b = (v2[q][j] - mu2) * rs2 * ((const float*)&Gs[q])[j] + ((const float*)&Bs[q])[j];
            if (q == 2) snv = b;
            gq[q] = a + b;
        }
        float rg = 1.f / (1.f + expf(-gq[0]));
        float ig = 1.f / (1.f + expf(-gq[1]));
        float lg = 1.f / (1.f + expf(-gq[3]));
        float ng = tanhf(gq[2] - rg * snv);
        float pp0 = ((const float*)&P0)[j], pp1 = ((const float*)&P1)[j];
        float hv = ng + ig * (lg * pp0 + (1.f - lg) * pp1 - ng);
        h[j] = hv; sh += hv; qh += hv * hv;
    }
    float r2[2] = {sh, qh};
#pragma unroll
    for (int off = 32; off > 0; off >>= 1) {
#pragma unroll
        for (int i = 0; i < 2; i++) r2[i] += __shfl_down(r2[i], off, 64);
    }
    if ((t & 63) == 0) {
        int w = t >> 6;
        sred[w * 4] = r2[0]; sred[w * 4 + 1] = r2[1];
    }
    __syncthreads();
    if (t == 0) {
        float S = 0, Q = 0;
        for (int w = 0; w < 4; w++) { S += sred[w * 4]; Q += sred[w * 4 + 1]; }
        float mu = S * (1.f / 1024.f);
        float var = Q * (1.f / 1024.f) - mu * mu;
        stats[4] = mu; stats[5] = rsqrtf(var + 1e-5f);
    }
    __syncthreads();
    const float muh = stats[4], rsh = stats[5];

    float4 Gh = *(const float4*)(lnh_g + t * 4);
    float4 Bh = *(const float4*)(lnh_b + t * 4);
    float4 O;
#pragma unroll
    for (int j = 0; j < 4; j++)
        ((float*)&O)[j] = (h[j] - muh) * rsh * ((const float*)&Gh)[j] + ((const float*)&Bh)[j];
    *(float4*)(out + (long)row * 1024 + t * 4) = O;
}

extern "C" void kernel_launch(void* const* d_in, const int* in_sizes, int n_in,
                              void* d_out, int out_size, void* d_ws, size_t ws_size,
                              hipStream_t stream) {
    const float* x     = (const float*)d_in[0];
    const float* s0    = (const float*)d_in[1];
    const float* s1    = (const float*)d_in[2];
    const float* Wi    = (const float*)d_in[3];
    const float* Ws    = (const float*)d_in[4];
    const float* lni_g = (const float*)d_in[5];
    const float* lni_b = (const float*)d_in[6];
    const float* lns_g = (const float*)d_in[7];
    const float* lns_b = (const float*)d_in[8];
    const float* lnh_g = (const float*)d_in[9];
    const float* lnh_b = (const float*)d_in[10];
    float* out = (float*)d_out;

    // ws: exactly 256 MB.
    //   [0,128MB)   = M1 region; temporarily hosts sb (64MB) + Wsb (16MB)
    //   [128,256MB) = M2 region
    char* wsb = (char*)d_ws;
    ushort_t* M1  = (ushort_t*)wsb;                          // 128 MB
    ushort_t* M2  = (ushort_t*)(wsb + (((size_t)128) << 20)); // 128 MB
    ushort_t* sb  = (ushort_t*)wsb;                          // 64 MB (aliases M1)
    ushort_t* Wsb = (ushort_t*)(wsb + (((size_t)64) << 20)); // 16 MB (aliases M1)

    // phase 1: bf16 casts for GEMM2
    cast_concat<<<32768, 256, 0, stream>>>(s0, s1, sb);
    cast_bf16<<<8192, 256, 0, stream>>>(Ws, Wsb, (long)4096 * 2048);

    dim3 g(4096 / 128, 16384 / 128);
    // phase 2: GEMM2 (bf16 fast path), writes M2
    gemm_bt<<<g, 256, 0, stream>>>(sb, Wsb, M2, 16384, 4096, 2048);
    // phase 3: GEMM1 (fp32 staging), writes M1 (clobbers sb/Wsb - now dead)
    gemm_bt_f32<<<g, 256, 0, stream>>>(x, Wi, M1, 16384, 4096, 1024);

    // phase 4: fused epilogue
    fuse_ln<<<16384, 256, 0, stream>>>(M1, M2, s0, s1, lni_g, lni_b, lns_g,
                                       lns_b, lnh_b != nullptr ? lnh_g : lnh_g, lnh_b, out);
}

// Round 4
// 817.717 us; speedup vs baseline: 1.1231x; 1.1231x over previous
//
#include <hip/hip_runtime.h>
#include <cstdint>

// LNGRU2dCell: B=16384, D=1024, S=1024
//   M1 = x @ Wi^T          (16384x4096, K=1024)
//   M2 = [s0|s1] @ Ws^T    (16384x4096, K=2048)
//   gates = LN(M1)*g1+b1 + LN(M2)*g2+b2 ; gate math ; out = LN(h)*gh+bh
//
// ws = 256 MB: M1 region [0,128MB) + M2 region [128,256MB).
// d_out (64 MB) doubles as cast scratch (harness re-poisons it; we fully
// overwrite it in the last kernel). Phase plan (all lifetimes disjoint):
//   1. sb(64MB)->d_out, Wsb(16MB)->M1 region   [bf16 casts]
//   2. GEMM2 bf16 (sb,Wsb) -> M2                [840 TF verified structure]
//   3. xb(32MB)+Wib(8MB)->d_out (sb dead)       [bf16 casts]
//   4. GEMM1 bf16 (xb,Wib) -> M1 (Wsb dead)
//   5. fuse_ln(M1,M2,s0,s1) -> d_out (xb/Wib dead)

typedef unsigned short ushort_t;
typedef __attribute__((ext_vector_type(8))) __bf16 bf16x8;
typedef __attribute__((ext_vector_type(4))) float f32x4;

__device__ __forceinline__ ushort_t f2b(float f) {  // RNE
    unsigned u = __float_as_uint(f);
    unsigned r = (u + 0x7fffu + ((u >> 16) & 1u)) >> 16;
    return (ushort_t)r;
}
__device__ __forceinline__ float b2f(ushort_t u) {
    return __uint_as_float(((unsigned)u) << 16);
}

__device__ __forceinline__ void gl_lds16(const void* g, void* l) {
    __builtin_amdgcn_global_load_lds(
        (const __attribute__((address_space(1))) unsigned int*)(uintptr_t)g,
        (__attribute__((address_space(3))) unsigned int*)(uintptr_t)l,
        16, 0, 0);
}

// ---------------- casts ----------------
__global__ __launch_bounds__(256) void cast_bf16(const float* __restrict__ src,
                                                 ushort_t* __restrict__ dst, long n) {
    long i = ((long)blockIdx.x * 256 + threadIdx.x) * 4;
    if (i + 3 < n) {
        float4 v = *(const float4*)(src + i);
        ushort4 u;
        u.x = f2b(v.x); u.y = f2b(v.y); u.z = f2b(v.z); u.w = f2b(v.w);
        *(ushort4*)(dst + i) = u;
    }
}

// dst is B x 2048, src0/src1 are B x 1024 each
__global__ __launch_bounds__(256) void cast_concat(const float* __restrict__ s0,
                                                   const float* __restrict__ s1,
                                                   ushort_t* __restrict__ dst) {
    long i = ((long)blockIdx.x * 256 + threadIdx.x) * 4;  // index in dst
    long row = i >> 11;
    int  col = (int)(i & 2047);
    const float* src = (col < 1024) ? (s0 + row * 1024 + col)
                                    : (s1 + row * 1024 + (col - 1024));
    float4 v = *(const float4*)src;
    ushort4 u;
    u.x = f2b(v.x); u.y = f2b(v.y); u.z = f2b(v.z); u.w = f2b(v.w);
    *(ushort4*)(dst + i) = u;
}

// ------- GEMM (bf16 in): C[MxN] = A[MxK] @ W[NxK]^T, fp32 accum, bf16 out ---
__global__ __launch_bounds__(256, 2) void gemm_bt(const ushort_t* __restrict__ A,
                                                  const ushort_t* __restrict__ W,
                                                  ushort_t* __restrict__ C,
                                                  int M, int N, int K) {
    __shared__ __align__(16) ushort_t As[128 * 32];
    __shared__ __align__(16) ushort_t Bs[128 * 32];

    const int t    = threadIdx.x;
    const int lane = t & 63;
    const int wave = t >> 6;
    const int wm   = (wave >> 1) * 64;
    const int wn   = (wave & 1) * 64;

    const int bm0 = blockIdx.y * 128;
    const int bn0 = blockIdx.x * 128;

    // staging: thread t stages row t>>2, cols (t&3)*8 .. +7 (16 B)
    const int sr = t >> 2;
    const int sc = (t & 3) * 8;
    const ushort_t* Ag = A + (long)(bm0 + sr) * K + sc;
    const ushort_t* Wg = W + (long)(bn0 + sr) * K + sc;

    f32x4 acc[4][4];
#pragma unroll
    for (int i = 0; i < 4; i++)
#pragma unroll
        for (int j = 0; j < 4; j++) acc[i][j] = (f32x4){0.f, 0.f, 0.f, 0.f};

    const int mrow = lane & 15;
    const int kgrp = (lane >> 4) * 8;

    for (int k0 = 0; k0 < K; k0 += 32) {
        gl_lds16(Ag + k0,                As + t * 8);
        gl_lds16(Ag + (long)64 * K + k0, As + 2048 + t * 8);
        gl_lds16(Wg + k0,                Bs + t * 8);
        gl_lds16(Wg + (long)64 * K + k0, Bs + 2048 + t * 8);
        __syncthreads();

        bf16x8 af[4], bfr[4];
#pragma unroll
        for (int i = 0; i < 4; i++)
            af[i] = *(const bf16x8*)&As[(wm + i * 16 + mrow) * 32 + kgrp];
#pragma unroll
        for (int j = 0; j < 4; j++)
            bfr[j] = *(const bf16x8*)&Bs[(wn + j * 16 + mrow) * 32 + kgrp];
#pragma unroll
        for (int i = 0; i < 4; i++)
#pragma unroll
            for (int j = 0; j < 4; j++)
                acc[i][j] = __builtin_amdgcn_mfma_f32_16x16x32_bf16(af[i], bfr[j], acc[i][j], 0, 0, 0);
        __syncthreads();
    }

    // C/D layout: col=lane&15, row=(lane>>4)*4+r  [m89/m91 verified]
    const int quad = lane >> 4;
#pragma unroll
    for (int i = 0; i < 4; i++)
#pragma unroll
        for (int j = 0; j < 4; j++)
#pragma unroll
            for (int r = 0; r < 4; r++) {
                int cm = bm0 + wm + i * 16 + quad * 4 + r;
                int cn = bn0 + wn + j * 16 + (lane & 15);
                C[(long)cm * N + cn] = f2b(acc[i][j][r]);
            }
}

// ---------------- fused LN(M1)+LN(M2) -> gates -> h -> LN(h) ----------------
__global__ __launch_bounds__(256) void fuse_ln(const ushort_t* __restrict__ M1,
                                               const ushort_t* __restrict__ M2,
                                               const float* __restrict__ p0,
                                               const float* __restrict__ p1,
                                               const float* __restrict__ lni_g,
                                               const float* __restrict__ lni_b,
                                               const float* __restrict__ lns_g,
                                               const float* __restrict__ lns_b,
                                               const float* __restrict__ lnh_g,
                                               const float* __restrict__ lnh_b,
                                               float* __restrict__ out) {
    const int row = blockIdx.x;
    const int t   = threadIdx.x;
    const long base = (long)row * 4096;

    __shared__ float sred[16];
    __shared__ float stats[8];

    float v1[4][4], v2[4][4];
    float s1 = 0.f, q1 = 0.f, s2 = 0.f, q2 = 0.f;
#pragma unroll
    for (int q = 0; q < 4; q++) {
        ushort4 a = *(const ushort4*)(M1 + base + q * 1024 + t * 4);
        ushort4 b = *(const ushort4*)(M2 + base + q * 1024 + t * 4);
        const ushort_t* ap = (const ushort_t*)&a;
        const ushort_t* bp = (const ushort_t*)&b;
#pragma unroll
        for (int j = 0; j < 4; j++) {
            float f1 = b2f(ap[j]); v1[q][j] = f1; s1 += f1; q1 += f1 * f1;
            float f2 = b2f(bp[j]); v2[q][j] = f2; s2 += f2; q2 += f2 * f2;
        }
    }
    float r4[4] = {s1, q1, s2, q2};
#pragma unroll
    for (int off = 32; off > 0; off >>= 1) {
#pragma unroll
        for (int i = 0; i < 4; i++) r4[i] += __shfl_down(r4[i], off, 64);
    }
    if ((t & 63) == 0) {
        int w = t >> 6;
#pragma unroll
        for (int i = 0; i < 4; i++) sred[w * 4 + i] = r4[i];
    }
    __syncthreads();
    if (t == 0) {
        float S1 = 0, Q1 = 0, S2 = 0, Q2 = 0;
        for (int w = 0; w < 4; w++) {
            S1 += sred[w * 4]; Q1 += sred[w * 4 + 1];
            S2 += sred[w * 4 + 2]; Q2 += sred[w * 4 + 3];
        }
        float mu1 = S1 * (1.f / 4096.f), mu2 = S2 * (1.f / 4096.f);
        float var1 = Q1 * (1.f / 4096.f) - mu1 * mu1;
        float var2 = Q2 * (1.f / 4096.f) - mu2 * mu2;
        stats[0] = mu1; stats[1] = rsqrtf(var1 + 1e-5f);
        stats[2] = mu2; stats[3] = rsqrtf(var2 + 1e-5f);
    }
    __syncthreads();
    const float mu1 = stats[0], rs1 = stats[1], mu2 = stats[2], rs2 = stats[3];

    float4 Gi[4], Bi[4], Gs[4], Bs[4];
#pragma unroll
    for (int q = 0; q < 4; q++) {
        Gi[q] = *(const float4*)(lni_g + q * 1024 + t * 4);
        Bi[q] = *(const float4*)(lni_b + q * 1024 + t * 4);
        Gs[q] = *(const float4*)(lns_g + q * 1024 + t * 4);
        Bs[q] = *(const float4*)(lns_b + q * 1024 + t * 4);
    }
    float4 P0 = *(const float4*)(p0 + (long)row * 1024 + t * 4);
    float4 P1 = *(const float4*)(p1 + (long)row * 1024 + t * 4);

    float h[4];
    float sh = 0.f, qh = 0.f;
#pragma unroll
    for (int j = 0; j < 4; j++) {
        float gq[4], snv = 0.f;
#pragma unroll
        for (int q = 0; q < 4; q++) {
            float a = (v1[q][j] - mu1) * rs1 * ((const float*)&Gi[q])[j] + ((const float*)&Bi[q])[j];
            float b = (v2[q][j] - mu2) * rs2 * ((const float*)&Gs[q])[j] + ((const float*)&Bs[q])[j];
            if (q == 2) snv = b;
            gq[q] = a + b;
        }
        float rg = 1.f / (1.f + expf(-gq[0]));
        float ig = 1.f / (1.f + expf(-gq[1]));
        float lg = 1.f / (1.f + expf(-gq[3]));
        float ng = tanhf(gq[2] - rg * snv);
        float pp0 = ((const float*)&P0)[j], pp1 = ((const float*)&P1)[j];
        float hv = ng + ig * (lg * pp0 + (1.f - lg) * pp1 - ng);
        h[j] = hv; sh += hv; qh += hv * hv;
    }
    float r2[2] = {sh, qh};
#pragma unroll
    for (int off = 32; off > 0; off >>= 1) {
#pragma unroll
        for (int i = 0; i < 2; i++) r2[i] += __shfl_down(r2[i], off, 64);
    }
    if ((t & 63) == 0) {
        int w = t >> 6;
        sred[w * 4] = r2[0]; sred[w * 4 + 1] = r2[1];
    }
    __syncthreads();
    if (t == 0) {
        float S = 0, Q = 0;
        for (int w = 0; w < 4; w++) { S += sred[w * 4]; Q += sred[w * 4 + 1]; }
        float mu = S * (1.f / 1024.f);
        float var = Q * (1.f / 1024.f) - mu * mu;
        stats[4] = mu; stats[5] = rsqrtf(var + 1e-5f);
    }
    __syncthreads();
    const float muh = stats[4], rsh = stats[5];

    float4 Gh = *(const float4*)(lnh_g + t * 4);
    float4 Bh = *(const float4*)(lnh_b + t * 4);
    float4 O;
#pragma unroll
    for (int j = 0; j < 4; j++)
        ((float*)&O)[j] = (h[j] - muh) * rsh * ((const float*)&Gh)[j] + ((const float*)&Bh)[j];
    *(float4*)(out + (long)row * 1024 + t * 4) = O;
}

extern "C" void kernel_launch(void* const* d_in, const int* in_sizes, int n_in,
                              void* d_out, int out_size, void* d_ws, size_t ws_size,
                              hipStream_t stream) {
    const float* x     = (const float*)d_in[0];
    const float* s0    = (const float*)d_in[1];
    const float* s1    = (const float*)d_in[2];
    const float* Wi    = (const float*)d_in[3];
    const float* Ws    = (const float*)d_in[4];
    const float* lni_g = (const float*)d_in[5];
    const float* lni_b = (const float*)d_in[6];
    const float* lns_g = (const float*)d_in[7];
    const float* lns_b = (const float*)d_in[8];
    const float* lnh_g = (const float*)d_in[9];
    const float* lnh_b = (const float*)d_in[10];
    float* out = (float*)d_out;

    // ws: 256 MB = M1 [0,128MB) + M2 [128,256MB). d_out = 64 MB cast scratch.
    char* wsb = (char*)d_ws;
    ushort_t* M1  = (ushort_t*)wsb;                           // 128 MB
    ushort_t* M2  = (ushort_t*)(wsb + (((size_t)128) << 20)); // 128 MB
    ushort_t* Wsb = (ushort_t*)wsb;                           // 16 MB, aliases M1 (dead)
    ushort_t* sb  = (ushort_t*)d_out;                         // 64 MB, aliases out
    ushort_t* xb  = (ushort_t*)d_out;                         // 32 MB, aliases out
    ushort_t* Wib = (ushort_t*)((char*)d_out + (((size_t)32) << 20));  // 8 MB

    dim3 g(4096 / 128, 16384 / 128);

    // phase 1: casts for GEMM2
    cast_concat<<<32768, 256, 0, stream>>>(s0, s1, sb);
    cast_bf16<<<8192, 256, 0, stream>>>(Ws, Wsb, (long)4096 * 2048);
    // phase 2: GEMM2 (K=2048) -> M2
    gemm_bt<<<g, 256, 0, stream>>>(sb, Wsb, M2, 16384, 4096, 2048);
    // phase 3: casts for GEMM1 (overwrite sb, now dead)
    cast_bf16<<<16384, 256, 0, stream>>>(x, xb, (long)16384 * 1024);
    cast_bf16<<<4096, 256, 0, stream>>>(Wi, Wib, (long)4096 * 1024);
    // phase 4: GEMM1 (K=1024) -> M1 (overwrites Wsb, now dead)
    gemm_bt<<<g, 256, 0, stream>>>(xb, Wib, M1, 16384, 4096, 1024);
    // phase 5: fused epilogue -> d_out (overwrites xb/Wib, now dead)
    fuse_ln<<<16384, 256, 0, stream>>>(M1, M2, s0, s1, lni_g, lni_b, lns_g,
                                       lns_b, lnh_g, lnh_b, out);
}

// Round 5
// 761.631 us; speedup vs baseline: 1.2058x; 1.0736x over previous
//
#include <hip/hip_runtime.h>
#include <cstdint>

// LNGRU2dCell: B=16384, D=1024, S=1024
//   M1 = x @ Wi^T          (16384x4096, K=1024)
//   M2 = [s0|s1] @ Ws^T    (16384x4096, K=2048)
//   gates = LN(M1)*g1+b1 + LN(M2)*g2+b2 ; gate math ; out = LN(h)*gh+bh
//
// ws = 256 MB: M1 region [0,128MB) + M2 region [128,256MB).
// d_out (64 MB) doubles as cast scratch. Phases (lifetimes disjoint):
//   1. sb(64MB)->d_out, Wsb(16MB)->M1 region   [bf16 casts]
//   2. GEMM2 bf16 (sb,Wsb) -> M2
//   3. xb(32MB)+Wib(8MB)->d_out (sb dead)
//   4. GEMM1 bf16 (xb,Wib) -> M1 (Wsb dead)
//   5. fuse_ln(M1,M2,s0,s1) -> d_out (xb/Wib dead)
//
// R4 changes: (a) GEMM BK=64 double-panel (halves barrier drains, the m97
// ~20% stall); (b) fuse_ln fast transcendentals (v_exp/v_rcp).

typedef unsigned short ushort_t;
typedef __attribute__((ext_vector_type(8))) __bf16 bf16x8;
typedef __attribute__((ext_vector_type(4))) float f32x4;

__device__ __forceinline__ ushort_t f2b(float f) {  // RNE
    unsigned u = __float_as_uint(f);
    unsigned r = (u + 0x7fffu + ((u >> 16) & 1u)) >> 16;
    return (ushort_t)r;
}
__device__ __forceinline__ float b2f(ushort_t u) {
    return __uint_as_float(((unsigned)u) << 16);
}

__device__ __forceinline__ void gl_lds16(const void* g, void* l) {
    __builtin_amdgcn_global_load_lds(
        (const __attribute__((address_space(1))) unsigned int*)(uintptr_t)g,
        (__attribute__((address_space(3))) unsigned int*)(uintptr_t)l,
        16, 0, 0);
}

// fast transcendentals: v_exp_f32 is 2^x, v_rcp_f32 ~1ulp — both far below
// the bf16 noise floor of this pipeline.
#define LOG2E 1.4426950408889634f
__device__ __forceinline__ float fexp2(float x) { return __builtin_amdgcn_exp2f(x); }
__device__ __forceinline__ float frcp(float x)  { return __builtin_amdgcn_rcpf(x); }
__device__ __forceinline__ float fsigmoid(float x) {
    return frcp(1.f + fexp2(-LOG2E * x));   // x=+inf -> 1, x=-inf -> 0
}
__device__ __forceinline__ float ftanh(float y) {
    return 1.f - 2.f * frcp(1.f + fexp2((2.f * LOG2E) * y));  // saturates +-1
}

// ---------------- casts ----------------
__global__ __launch_bounds__(256) void cast_bf16(const float* __restrict__ src,
                                                 ushort_t* __restrict__ dst, long n) {
    long i = ((long)blockIdx.x * 256 + threadIdx.x) * 4;
    if (i + 3 < n) {
        float4 v = *(const float4*)(src + i);
        ushort4 u;
        u.x = f2b(v.x); u.y = f2b(v.y); u.z = f2b(v.z); u.w = f2b(v.w);
        *(ushort4*)(dst + i) = u;
    }
}

// dst is B x 2048, src0/src1 are B x 1024 each
__global__ __launch_bounds__(256) void cast_concat(const float* __restrict__ s0,
                                                   const float* __restrict__ s1,
                                                   ushort_t* __restrict__ dst) {
    long i = ((long)blockIdx.x * 256 + threadIdx.x) * 4;  // index in dst
    long row = i >> 11;
    int  col = (int)(i & 2047);
    const float* src = (col < 1024) ? (s0 + row * 1024 + col)
                                    : (s1 + row * 1024 + (col - 1024));
    float4 v = *(const float4*)src;
    ushort4 u;
    u.x = f2b(v.x); u.y = f2b(v.y); u.z = f2b(v.z); u.w = f2b(v.w);
    *(ushort4*)(dst + i) = u;
}

// ------- GEMM (bf16 in): C[MxN] = A[MxK] @ W[NxK]^T, fp32 accum, bf16 out ---
// BK=64: two 128x32 panels staged per barrier (half the vmcnt(0) drains of
// the BK=32 structure). Panel-internal layout identical to verified m97.
__global__ __launch_bounds__(256, 2) void gemm_bt(const ushort_t* __restrict__ A,
                                                  const ushort_t* __restrict__ W,
                                                  ushort_t* __restrict__ C,
                                                  int M, int N, int K) {
    __shared__ __align__(16) ushort_t As[2][128 * 32];
    __shared__ __align__(16) ushort_t Bs[2][128 * 32];

    const int t    = threadIdx.x;
    const int lane = t & 63;
    const int wave = t >> 6;
    const int wm   = (wave >> 1) * 64;
    const int wn   = (wave & 1) * 64;

    const int bm0 = blockIdx.y * 128;
    const int bn0 = blockIdx.x * 128;

    // staging: thread t stages row t>>2, cols (t&3)*8 .. +7 (16 B)
    const int sr = t >> 2;
    const int sc = (t & 3) * 8;
    const ushort_t* Ag = A + (long)(bm0 + sr) * K + sc;
    const ushort_t* Wg = W + (long)(bn0 + sr) * K + sc;

    f32x4 acc[4][4];
#pragma unroll
    for (int i = 0; i < 4; i++)
#pragma unroll
        for (int j = 0; j < 4; j++) acc[i][j] = (f32x4){0.f, 0.f, 0.f, 0.f};

    const int mrow = lane & 15;
    const int kgrp = (lane >> 4) * 8;

    for (int k0 = 0; k0 < K; k0 += 64) {
#pragma unroll
        for (int h = 0; h < 2; h++) {
            int kh = k0 + h * 32;
            gl_lds16(Ag + kh,                As[h] + t * 8);
            gl_lds16(Ag + (long)64 * K + kh, As[h] + 2048 + t * 8);
            gl_lds16(Wg + kh,                Bs[h] + t * 8);
            gl_lds16(Wg + (long)64 * K + kh, Bs[h] + 2048 + t * 8);
        }
        __syncthreads();

#pragma unroll
        for (int h = 0; h < 2; h++) {
            bf16x8 af[4], bfr[4];
#pragma unroll
            for (int i = 0; i < 4; i++)
                af[i] = *(const bf16x8*)&As[h][(wm + i * 16 + mrow) * 32 + kgrp];
#pragma unroll
            for (int j = 0; j < 4; j++)
                bfr[j] = *(const bf16x8*)&Bs[h][(wn + j * 16 + mrow) * 32 + kgrp];
#pragma unroll
            for (int i = 0; i < 4; i++)
#pragma unroll
                for (int j = 0; j < 4; j++)
                    acc[i][j] = __builtin_amdgcn_mfma_f32_16x16x32_bf16(af[i], bfr[j], acc[i][j], 0, 0, 0);
        }
        __syncthreads();
    }

    // C/D layout: col=lane&15, row=(lane>>4)*4+r  [m89/m91 verified]
    const int quad = lane >> 4;
#pragma unroll
    for (int i = 0; i < 4; i++)
#pragma unroll
        for (int j = 0; j < 4; j++)
#pragma unroll
            for (int r = 0; r < 4; r++) {
                int cm = bm0 + wm + i * 16 + quad * 4 + r;
                int cn = bn0 + wn + j * 16 + (lane & 15);
                C[(long)cm * N + cn] = f2b(acc[i][j][r]);
            }
}

// ---------------- fused LN(M1)+LN(M2) -> gates -> h -> LN(h) ----------------
__global__ __launch_bounds__(256) void fuse_ln(const ushort_t* __restrict__ M1,
                                               const ushort_t* __restrict__ M2,
                                               const float* __restrict__ p0,
                                               const float* __restrict__ p1,
                                               const float* __restrict__ lni_g,
                                               const float* __restrict__ lni_b,
                                               const float* __restrict__ lns_g,
                                               const float* __restrict__ lns_b,
                                               const float* __restrict__ lnh_g,
                                               const float* __restrict__ lnh_b,
                                               float* __restrict__ out) {
    const int row = blockIdx.x;
    const int t   = threadIdx.x;
    const long base = (long)row * 4096;

    __shared__ float sred[16];
    __shared__ float stats[8];

    float v1[4][4], v2[4][4];
    float s1 = 0.f, q1 = 0.f, s2 = 0.f, q2 = 0.f;
#pragma unroll
    for (int q = 0; q < 4; q++) {
        ushort4 a = *(const ushort4*)(M1 + base + q * 1024 + t * 4);
        ushort4 b = *(const ushort4*)(M2 + base + q * 1024 + t * 4);
        const ushort_t* ap = (const ushort_t*)&a;
        const ushort_t* bp = (const ushort_t*)&b;
#pragma unroll
        for (int j = 0; j < 4; j++) {
            float f1 = b2f(ap[j]); v1[q][j] = f1; s1 += f1; q1 += f1 * f1;
            float f2 = b2f(bp[j]); v2[q][j] = f2; s2 += f2; q2 += f2 * f2;
        }
    }
    float r4[4] = {s1, q1, s2, q2};
#pragma unroll
    for (int off = 32; off > 0; off >>= 1) {
#pragma unroll
        for (int i = 0; i < 4; i++) r4[i] += __shfl_down(r4[i], off, 64);
    }
    if ((t & 63) == 0) {
        int w = t >> 6;
#pragma unroll
        for (int i = 0; i < 4; i++) sred[w * 4 + i] = r4[i];
    }
    __syncthreads();
    if (t == 0) {
        float S1 = 0, Q1 = 0, S2 = 0, Q2 = 0;
        for (int w = 0; w < 4; w++) {
            S1 += sred[w * 4]; Q1 += sred[w * 4 + 1];
            S2 += sred[w * 4 + 2]; Q2 += sred[w * 4 + 3];
        }
        float mu1 = S1 * (1.f / 4096.f), mu2 = S2 * (1.f / 4096.f);
        float var1 = Q1 * (1.f / 4096.f) - mu1 * mu1;
        float var2 = Q2 * (1.f / 4096.f) - mu2 * mu2;
        stats[0] = mu1; stats[1] = rsqrtf(var1 + 1e-5f);
        stats[2] = mu2; stats[3] = rsqrtf(var2 + 1e-5f);
    }
    __syncthreads();
    const float mu1 = stats[0], rs1 = stats[1], mu2 = stats[2], rs2 = stats[3];

    float4 Gi[4], Bi[4], Gs[4], Bs[4];
#pragma unroll
    for (int q = 0; q < 4; q++) {
        Gi[q] = *(const float4*)(lni_g + q * 1024 + t * 4);
        Bi[q] = *(const float4*)(lni_b + q * 1024 + t * 4);
        Gs[q] = *(const float4*)(lns_g + q * 1024 + t * 4);
        Bs[q] = *(const float4*)(lns_b + q * 1024 + t * 4);
    }
    float4 P0 = *(const float4*)(p0 + (long)row * 1024 + t * 4);
    float4 P1 = *(const float4*)(p1 + (long)row * 1024 + t * 4);

    float h[4];
    float sh = 0.f, qh = 0.f;
#pragma unroll
    for (int j = 0; j < 4; j++) {
        float gq[4], snv = 0.f;
#pragma unroll
        for (int q = 0; q < 4; q++) {
            float a = (v1[q][j] - mu1) * rs1 * ((const float*)&Gi[q])[j] + ((const float*)&Bi[q])[j];
            float b = (v2[q][j] - mu2) * rs2 * ((const float*)&Gs[q])[j] + ((const float*)&Bs[q])[j];
            if (q == 2) snv = b;
            gq[q] = a + b;
        }
        float rg = fsigmoid(gq[0]);
        float ig = fsigmoid(gq[1]);
        float lg = fsigmoid(gq[3]);
        float ng = ftanh(gq[2] - rg * snv);
        float pp0 = ((const float*)&P0)[j], pp1 = ((const float*)&P1)[j];
        float hv = ng + ig * (lg * pp0 + (1.f - lg) * pp1 - ng);
        h[j] = hv; sh += hv; qh += hv * hv;
    }
    float r2[2] = {sh, qh};
#pragma unroll
    for (int off = 32; off > 0; off >>= 1) {
#pragma unroll
        for (int i = 0; i < 2; i++) r2[i] += __shfl_down(r2[i], off, 64);
    }
    if ((t & 63) == 0) {
        int w = t >> 6;
        sred[w * 4] = r2[0]; sred[w * 4 + 1] = r2[1];
    }
    __syncthreads();
    if (t == 0) {
        float S = 0, Q = 0;
        for (int w = 0; w < 4; w++) { S += sred[w * 4]; Q += sred[w * 4 + 1]; }
        float mu = S * (1.f / 1024.f);
        float var = Q * (1.f / 1024.f) - mu * mu;
        stats[4] = mu; stats[5] = rsqrtf(var + 1e-5f);
    }
    __syncthreads();
    const float muh = stats[4], rsh = stats[5];

    float4 Gh = *(const float4*)(lnh_g + t * 4);
    float4 Bh = *(const float4*)(lnh_b + t * 4);
    float4 O;
#pragma unroll
    for (int j = 0; j < 4; j++)
        ((float*)&O)[j] = (h[j] - muh) * rsh * ((const float*)&Gh)[j] + ((const float*)&Bh)[j];
    *(float4*)(out + (long)row * 1024 + t * 4) = O;
}

extern "C" void kernel_launch(void* const* d_in, const int* in_sizes, int n_in,
                              void* d_out, int out_size, void* d_ws, size_t ws_size,
                              hipStream_t stream) {
    const float* x     = (const float*)d_in[0];
    const float* s0    = (const float*)d_in[1];
    const float* s1    = (const float*)d_in[2];
    const float* Wi    = (const float*)d_in[3];
    const float* Ws    = (const float*)d_in[4];
    const float* lni_g = (const float*)d_in[5];
    const float* lni_b = (const float*)d_in[6];
    const float* lns_g = (const float*)d_in[7];
    const float* lns_b = (const float*)d_in[8];
    const float* lnh_g = (const float*)d_in[9];
    const float* lnh_b = (const float*)d_in[10];
    float* out = (float*)d_out;

    // ws: 256 MB = M1 [0,128MB) + M2 [128,256MB). d_out = 64 MB cast scratch.
    char* wsb = (char*)d_ws;
    ushort_t* M1  = (ushort_t*)wsb;                           // 128 MB
    ushort_t* M2  = (ushort_t*)(wsb + (((size_t)128) << 20)); // 128 MB
    ushort_t* Wsb = (ushort_t*)wsb;                           // 16 MB, aliases M1 (dead)
    ushort_t* sb  = (ushort_t*)d_out;                         // 64 MB, aliases out
    ushort_t* xb  = (ushort_t*)d_out;                         // 32 MB, aliases out
    ushort_t* Wib = (ushort_t*)((char*)d_out + (((size_t)32) << 20));  // 8 MB

    dim3 g(4096 / 128, 16384 / 128);

    // phase 1: casts for GEMM2
    cast_concat<<<32768, 256, 0, stream>>>(s0, s1, sb);
    cast_bf16<<<8192, 256, 0, stream>>>(Ws, Wsb, (long)4096 * 2048);
    // phase 2: GEMM2 (K=2048) -> M2
    gemm_bt<<<g, 256, 0, stream>>>(sb, Wsb, M2, 16384, 4096, 2048);
    // phase 3: casts for GEMM1 (overwrite sb, now dead)
    cast_bf16<<<16384, 256, 0, stream>>>(x, xb, (long)16384 * 1024);
    cast_bf16<<<4096, 256, 0, stream>>>(Wi, Wib, (long)4096 * 1024);
    // phase 4: GEMM1 (K=1024) -> M1 (overwrites Wsb, now dead)
    gemm_bt<<<g, 256, 0, stream>>>(xb, Wib, M1, 16384, 4096, 1024);
    // phase 5: fused epilogue -> d_out (overwrites xb/Wib, now dead)
    fuse_ln<<<16384, 256, 0, stream>>>(M1, M2, s0, s1, lni_g, lni_b, lns_g,
                                       lns_b, lnh_g, lnh_b, out);
}